// Round 1
// 426.409 us; speedup vs baseline: 1.0137x; 1.0137x over previous
//
#include <hip/hip_runtime.h>

// Problem constants (fixed by setup_inputs in the reference):
//   x:        (64, 4, 512, 512) f32
//   cls_token:(1, 1, 1024)      f32
//   pos_emb:  (1, 1025, 1024)   f32
//   out:      (64, 1025, 1024)  f32
// out[b, 1+i, j] = x[b, c, xi*16+pi, yi*16+pj] + pos_emb[0, 1+i, j]
//   where i = c*256 + pi*16 + pj  and (xi, yi) = hilbert_d2xy(j) on 32x32 grid
// out[b, 0, e] = cls_token[e] + pos_emb[0, 0, e]
//
// Key structural fact: the Hilbert curve visits each ALIGNED 8x8 patch block
// in one contiguous d-range of 64 (recursive 4^k property). So the 64 output
// columns j0..j0+63 of a tile correspond to a contiguous 128x128-pixel source
// region -> fully coalesced 1KB/wave reads; the Hilbert permutation is done
// in LDS addressing (scalar writes), not in global access patterns.
//
// This revision vs the 432 µs baseline:
//  * cls row folded in as 64 leading blocks (removes a serialized graph node)
//  * nontemporal loads on x / nontemporal stores on out (read-once/write-once
//    streams should not thrash the 4 MiB/XCD L2 where pos_emb lives; pos_emb
//    is re-read 64x and we want it L2-resident)
//  * LDS layout untouched: stride-68 pad puts same-jl write collisions at
//    2-way (free, m136); remaining conflicts are Hilbert-data-dependent and
//    not removable by lane-uniform swizzles; b128 read phase is already even.

#define NGRID 32
#define PSZ   16
#define CH    4
#define HW    512     // NGRID * PSZ
#define EMB   1024
#define SEQ   1025
#define LDS_STRIDE 68 // 64 + 4 pad: spreads ds accesses over 32 banks

typedef float f32x4 __attribute__((ext_vector_type(4)));

// Standard Hilbert d -> (x, y) (matches the Python _d2xy reference exactly).
__device__ __forceinline__ void d2xy(int d, int& xo, int& yo) {
    int x = 0, y = 0, t = d;
    #pragma unroll
    for (int s = 1; s < NGRID; s <<= 1) {
        int rx = 1 & (t >> 1);
        int ry = 1 & (t ^ rx);
        if (ry == 0) {
            if (rx == 1) { x = s - 1 - x; y = s - 1 - y; }
            int tmp = x; x = y; y = tmp;
        }
        x += s * rx;
        y += s * ry;
        t >>= 2;
    }
    xo = x; yo = y;
}

// Standard inverse: (x, y) -> Hilbert distance d (exact inverse of d2xy).
__device__ __forceinline__ int xy2d(int x, int y) {
    int d = 0;
    #pragma unroll
    for (int s = NGRID / 2; s > 0; s >>= 1) {
        int rx = (x & s) ? 1 : 0;
        int ry = (y & s) ? 1 : 0;
        d += s * s * ((3 * rx) ^ ry);
        if (ry == 0) {
            if (rx == 1) { x = s - 1 - x; y = s - 1 - y; }
            int tmp = x; x = y; y = tmp;
        }
    }
    return d;
}

// Blocks 0..63:      cls row  (out[b,0,:] = cls_token + pos_emb[0,0,:])
// Blocks 64..16447:  one (b, 64-wide i-block, 64-wide j-block) tile each.
__global__ __launch_bounds__(256) void hilbert_patch_kernel(
    const float* __restrict__ x,
    const float* __restrict__ cls_token,
    const float* __restrict__ pos_emb,
    float* __restrict__ out)
{
    __shared__ float tile[64 * LDS_STRIDE];  // 17408 B

    if (blockIdx.x < 64) {
        // ---- cls row path: 64 blocks * 256 threads = 16384 float4s ----
        const int t  = blockIdx.x * 256 + threadIdx.x;
        const int b  = t >> 8;                          // 256 float4 per row
        const int e4 = t & 255;
        f32x4 cv = ((const f32x4*)cls_token)[e4];
        f32x4 pv = ((const f32x4*)pos_emb)[e4];
        cv += pv;
        ((f32x4*)(out + (size_t)b * SEQ * EMB))[e4] = cv;
        return;
    }

    const int blk = blockIdx.x - 64;
    const int b   = blk >> 8;        // / 256
    const int rem = blk & 255;
    const int ib  = rem >> 4;        // i-block index 0..15
    const int jb  = rem & 15;        // j-block index 0..15
    const int i0  = ib << 6;         // * 64
    const int j0  = jb << 6;
    const int c   = i0 >> 8;         // channel (i-block of 64 stays in one c)
    const int pi0 = (i0 >> 4) & 15;  // first of 4 consecutive pi rows

    const int t = threadIdx.x;

    // ---- load phase: contiguous x region -> LDS (Hilbert-permuted) ----
    // The j-block's 64 patches form one aligned 8x8 patch block. Each thread
    // owns one patch-column-slice: patch (xi8, yi8), 4-float pj slice, and
    // iterates the 4 pi rows. Wave = 2 x 512B contiguous segments per load.
    {
        // Locate the 8x8 patch block from the first Hilbert index (uniform).
        int x0, y0;
        d2xy(j0, x0, y0);
        const int xb = x0 & ~7;
        const int yb = y0 & ~7;

        const int xi8 = t >> 5;        // 0..7
        const int f   = t & 31;        // float4 column within 128-px row
        const int yi8 = f >> 2;        // 0..7
        const int pj0 = (f & 3) * 4;   // 0,4,8,12

        const int xi = xb + xi8;
        const int yi = yb + yi8;
        const int jl = xy2d(xi, yi) - j0;   // Hilbert-local column, 0..63

        const float* xbase = x
            + ((size_t)(b * CH + c) * HW + (size_t)(xi * PSZ + pi0)) * HW
            + (size_t)(yi * PSZ + pj0);
        #pragma unroll
        for (int k = 0; k < 4; ++k) {       // pi = pi0 + k
            f32x4 v = __builtin_nontemporal_load(
                (const f32x4*)(xbase + (size_t)k * HW));
            const int ilb = k * 16 + pj0;   // il = (pi-pi0)*16 + pj
            tile[(ilb + 0) * LDS_STRIDE + jl] = v.x;
            tile[(ilb + 1) * LDS_STRIDE + jl] = v.y;
            tile[(ilb + 2) * LDS_STRIDE + jl] = v.z;
            tile[(ilb + 3) * LDS_STRIDE + jl] = v.w;
        }
    }
    __syncthreads();

    // ---- store phase: LDS -> out rows, fused pos_emb add ----
    // 16 lanes write one contiguous 256B output row segment; 4 rows/wave.
    {
        const int f = t & 15;        // float4 index along j
        const int r = t >> 4;        // row base 0..15
        #pragma unroll
        for (int k = 0; k < 4; ++k) {
            const int il = r + k * 16;
            const int i  = i0 + il;
            const size_t col = (size_t)j0 + f * 4;
            f32x4 w  = *(const f32x4*)&tile[il * LDS_STRIDE + f * 4];
            f32x4 pe = *(const f32x4*)(pos_emb + (size_t)(1 + i) * EMB + col);
            w += pe;
            __builtin_nontemporal_store(
                w, (f32x4*)(out + ((size_t)b * SEQ + 1 + i) * EMB + col));
        }
    }
}

extern "C" void kernel_launch(void* const* d_in, const int* in_sizes, int n_in,
                              void* d_out, int out_size, void* d_ws, size_t ws_size,
                              hipStream_t stream) {
    const float* x   = (const float*)d_in[0];
    const float* cls = (const float*)d_in[1];
    const float* pos = (const float*)d_in[2];
    float* out = (float*)d_out;

    // 64 cls blocks lead (they drain instantly, no tail-wave quantization),
    // then 64*16*16 = 16384 tile blocks.
    hipLaunchKernelGGL(hilbert_patch_kernel, dim3(64 + 64 * 16 * 16), dim3(256),
                       0, stream, x, cls, pos, out);
}